// Round 5
// baseline (1639.629 us; speedup 1.0000x reference)
//
#include <hip/hip_runtime.h>
#include <stdint.h>

#define NN   50000
#define INC  512
#define OUTC 128
#define NB   782      // ceil(50000/64) buckets of 64 nodes
#define CAP  4096     // per-bucket capacity (mean 2046, sigma ~45)
#define NWG  256      // scatter workgroups

typedef unsigned int  uint;
typedef unsigned short u16;
typedef short bf16x8 __attribute__((ext_vector_type(8)));
typedef float f32x4  __attribute__((ext_vector_type(4)));
typedef u16   u16x8  __attribute__((ext_vector_type(8)));
typedef u16   u16x4  __attribute__((ext_vector_type(4)));

__device__ __forceinline__ u16 f2bf(float f) {        // RNE f32->bf16
  uint u = __float_as_uint(f);
  u += 0x7fffu + ((u >> 16) & 1u);
  return (u16)(u >> 16);
}
__device__ __forceinline__ float bflo(uint v) { return __uint_as_float(v << 16); }
__device__ __forceinline__ float bfhi(uint v) { return __uint_as_float(v & 0xffff0000u); }

// ---------------- bucketed edge binning ----------------
// pairs[b*CAP + i] = src | (dst_local << 16); bucket_cursor[b*16] = count(b)
__global__ __launch_bounds__(256) void k_scatter_pairs(const int* __restrict__ src,
                                                       const int* __restrict__ dst, int E,
                                                       uint* __restrict__ bucket_cursor,
                                                       uint* __restrict__ pairs) {
  __shared__ uint hist[NB];
  __shared__ uint base[NB];
  __shared__ uint cur[NB];
  const int t = threadIdx.x;
  const int chunk = (E + NWG - 1) / NWG;
  const int e0 = blockIdx.x * chunk;
  const int e1 = min(e0 + chunk, E);

  for (int i = t; i < NB; i += 256) hist[i] = 0;
  __syncthreads();
  for (int e = e0 + t; e < e1; e += 256) {
    int b = dst[e] >> 6;
    atomicAdd(&hist[b], 1u);
  }
  __syncthreads();
  for (int i = t; i < NB; i += 256) {
    uint c = hist[i];
    base[i] = c ? atomicAdd(&bucket_cursor[i * 16], c) : 0u;
    cur[i] = 0;
  }
  __syncthreads();
  for (int e = e0 + t; e < e1; e += 256) {
    int d = dst[e];
    int b = d >> 6;
    uint r = atomicAdd(&cur[b], 1u);
    uint off = base[b] + r;
    if (off < CAP) pairs[(size_t)b * CAP + off] = (uint)src[e] | ((uint)(d & 63) << 16);
  }
}

// ---------------- per-node degree -> dis, from bucketed pairs ----------------
__global__ __launch_bounds__(64) void k_deg_dis(const uint* __restrict__ bucket_cursor,
                                                const uint* __restrict__ pairs,
                                                float* __restrict__ dis) {
  __shared__ uint cnt[64];
  const int b = blockIdx.x, t = threadIdx.x;
  cnt[t] = 0;
  __syncthreads();
  const uint n_e = bucket_cursor[b * 16];
  const uint* p = pairs + (size_t)b * CAP;
  for (uint e = t; e < n_e; e += 64) atomicAdd(&cnt[(p[e] >> 16) & 63], 1u);
  __syncthreads();
  int n = b * 64 + t;
  if (n < NN) dis[n] = rsqrtf((float)cnt[t] + 1.0f);
}

// ---------------- weight prep: transpose + bf16 + pre-swizzle ----------------
__global__ __launch_bounds__(256) void k_prep_enc(const float* __restrict__ W,   // [512][128]
                                                  uint8_t* __restrict__ outw) {
  __shared__ float t[32][128];
  const int tid = threadIdx.x;
  const int k0 = blockIdx.x * 32;
#pragma unroll
  for (int r = 0; r < 16; ++r) {
    int e = r * 256 + tid;
    int kk = e >> 7, n = e & 127;
    t[kk][n] = W[(size_t)(k0 + kk) * 128 + n];
  }
  __syncthreads();
#pragma unroll
  for (int it = 0; it < 2; ++it) {
    int item = it * 256 + tid;
    int n = item & 127, kc = item >> 7;
    int kg = k0 + kc * 8;
    int q = kg >> 7, kin = kg & 127;
    u16x8 p;
#pragma unroll
    for (int j = 0; j < 8; ++j) p[j] = f2bf(t[kc * 8 + j][n]);
    *(u16x8*)(outw + q * 32768 + ((((uint)n * 256) + (uint)kin * 2) ^ (uint)((n & 7) << 4))) = p;
  }
}
__global__ __launch_bounds__(256) void k_prep_dec(const float* __restrict__ W,   // [128][512]
                                                  uint8_t* __restrict__ outw) {
  __shared__ float t[128][32];
  const int tid = threadIdx.x;
  const int n0 = blockIdx.x * 32;
#pragma unroll
  for (int r = 0; r < 16; ++r) {
    int e = r * 256 + tid;
    int k = e >> 5, nl = e & 31;
    t[k][nl] = W[(size_t)k * 512 + n0 + nl];
  }
  __syncthreads();
#pragma unroll
  for (int it = 0; it < 2; ++it) {
    int item = it * 256 + tid;
    int nl = item & 31, kc = item >> 5;
    int n = n0 + nl;
    int c = n >> 7, nin = n & 127;
    u16x8 p;
#pragma unroll
    for (int j = 0; j < 8; ++j) p[j] = f2bf(t[kc * 8 + j][nl]);
    *(u16x8*)(outw + c * 32768 + ((((uint)nin * 256) + (uint)kc * 16) ^ (uint)((nin & 7) << 4))) = p;
  }
}

// ---------------- GEMM1 (MFMA): xws = bf16( (x @ W_enc) * dis[row] ) ----------------
__global__ __launch_bounds__(256, 2) void k_gemm1(const float* __restrict__ x,
                                                  const uint8_t* __restrict__ WtE,
                                                  const float* __restrict__ dis,
                                                  u16* __restrict__ xws) {
  __shared__ __align__(16) uint8_t lds[49152];
  uint8_t* WL = lds;            // 32768
  uint8_t* XL = lds + 32768;    // 16384: [128 rows][64 k] bf16 swizzled
  const int tid = threadIdx.x, lane = tid & 63, wv = tid >> 6;
  const int lane15 = lane & 15, laneh = lane >> 4;
  const int rb = blockIdx.x * 128;

  f32x4 acc[2][8];
#pragma unroll
  for (int m = 0; m < 2; ++m)
#pragma unroll
    for (int n = 0; n < 8; ++n) acc[m][n] = (f32x4){0.f, 0.f, 0.f, 0.f};

  const int srow = tid >> 1;
  int grow = rb + srow; if (grow >= NN) grow = NN - 1;
  const int khalf = (tid & 1) * 32;
  const uint xb  = (uint)srow * 128 + (uint)khalf * 2;
  const uint xsw = (uint)((srow & 7) << 4);
  const int ar0 = wv * 32 + lane15, ar1 = ar0 + 16;

  for (int q = 0; q < 4; ++q) {           // K quarters of 128
    __syncthreads();
    { const u16x8* s = (const u16x8*)(WtE + q * 32768);
      u16x8* d = (u16x8*)WL;
#pragma unroll
      for (int i = 0; i < 8; ++i) d[tid + i * 256] = s[tid + i * 256]; }
#pragma unroll
    for (int step = 0; step < 2; ++step) {  // BK = 64
      if (step) __syncthreads();
      const float4* xs = (const float4*)(x + (size_t)grow * INC + q * 128 + step * 64 + khalf);
      float4 v[8];
#pragma unroll
      for (int j = 0; j < 8; ++j) v[j] = xs[j];
#pragma unroll
      for (int j = 0; j < 8; ++j) {
        u16x4 p; p.x = f2bf(v[j].x); p.y = f2bf(v[j].y); p.z = f2bf(v[j].z); p.w = f2bf(v[j].w);
        *(u16x4*)(XL + ((xb + j * 8) ^ xsw)) = p;
      }
      __syncthreads();
#pragma unroll
      for (int kk = 0; kk < 2; ++kk) {     // k-slices of 32
        bf16x8 a0 = *(const bf16x8*)(XL + (((uint)ar0 * 128 + kk * 64 + laneh * 16) ^ (uint)((ar0 & 7) << 4)));
        bf16x8 a1 = *(const bf16x8*)(XL + (((uint)ar1 * 128 + kk * 64 + laneh * 16) ^ (uint)((ar1 & 7) << 4)));
#pragma unroll
        for (int nf = 0; nf < 8; ++nf) {
          int n = nf * 16 + lane15;
          bf16x8 b = *(const bf16x8*)(WL + (((uint)n * 256 + step * 128 + kk * 64 + laneh * 16) ^ (uint)((n & 7) << 4)));
          acc[0][nf] = __builtin_amdgcn_mfma_f32_16x16x32_bf16(a0, b, acc[0][nf], 0, 0, 0);
          acc[1][nf] = __builtin_amdgcn_mfma_f32_16x16x32_bf16(a1, b, acc[1][nf], 0, 0, 0);
        }
      }
    }
  }
#pragma unroll
  for (int m = 0; m < 2; ++m) {
#pragma unroll
    for (int r = 0; r < 4; ++r) {
      int row = rb + wv * 32 + m * 16 + laneh * 4 + r;
      if (row < NN) {
        float dv = dis[row];
#pragma unroll
        for (int nf = 0; nf < 8; ++nf)
          xws[(size_t)row * 128 + nf * 16 + lane15] = f2bf(acc[m][nf][r] * dv);
      }
    }
  }
}

// ---------------- fused aggregate: LDS z-acc per 64-node bucket ----------------
__global__ __launch_bounds__(256) void k_agg(const uint* __restrict__ bucket_cursor,
                                             const uint* __restrict__ pairs,
                                             const uint* __restrict__ xws32,   // xws as uint (2ch)
                                             const float* __restrict__ dis,
                                             const float* __restrict__ bias,
                                             uint8_t* __restrict__ zsw) {
  __shared__ float zacc[64 * 128];   // 32 KB
  const int b = blockIdx.x, t = threadIdx.x;
  const int lane = t & 63, wv = t >> 6;
#pragma unroll
  for (int i = 0; i < 32; ++i) zacc[t + i * 256] = 0.f;
  __syncthreads();

  const uint n_e = bucket_cursor[b * 16];
  const uint* p = pairs + (size_t)b * CAP;
  const int k = lane >> 1;
  const bool hi = lane & 1;
  for (uint e = wv; e < n_e; e += 4) {      // one edge per wave
    uint v = p[e];
    uint src = v & 0xffffu;
    uint dl  = (v >> 16) & 63u;
    uint u0 = xws32[(size_t)src * 64 + k];
    uint u1 = xws32[(size_t)src * 64 + 32 + k];
    float f0 = hi ? bfhi(u0) : bflo(u0);    // channel = lane
    float f1 = hi ? bfhi(u1) : bflo(u1);    // channel = lane + 64
    atomicAdd(&zacc[dl * 128 + lane], f0);
    atomicAdd(&zacc[dl * 128 + 64 + lane], f1);
  }
  __syncthreads();

  // epilogue: z = relu(dis*(acc + self) + bias), store swizzled bf16
#pragma unroll
  for (int i = 0; i < 16; ++i) {
    int idx = i * 256 + t;          // 0..4095
    int row = idx >> 6, cu = idx & 63;
    int n = b * 64 + row;
    if (n < NN) {
      uint us = xws32[(size_t)n * 64 + cu];
      float di = dis[n];
      float2 bb = *(const float2*)(bias + cu * 2);
      float z0 = fmaxf(di * (zacc[row * 128 + cu * 2]     + bflo(us)) + bb.x, 0.f);
      float z1 = fmaxf(di * (zacc[row * 128 + cu * 2 + 1] + bfhi(us)) + bb.y, 0.f);
      uint pk = (uint)f2bf(z0) | ((uint)f2bf(z1) << 16);
      *(uint*)(zsw + ((((uint)n * 256) + (uint)cu * 4) ^ (uint)((n & 7) << 4))) = pk;
    }
  }
}

// ---------------- decode (MFMA): out = softmax(z @ W_dec) ----------------
__global__ __launch_bounds__(512, 2) void k_decode(const uint8_t* __restrict__ zsw,
                                                   const uint8_t* __restrict__ WtD,
                                                   float* __restrict__ out) {
  __shared__ __align__(16) uint8_t lds[65536];
  uint8_t* ZL = lds;
  uint8_t* WL = lds + 32768;
  const int tid = threadIdx.x, lane = tid & 63, wv = tid >> 6;
  const int lane15 = lane & 15, laneh = lane >> 4;
  const int rb = blockIdx.x * 128;

  { const u16x8* s = (const u16x8*)(zsw + (size_t)rb * 256);
    u16x8* d = (u16x8*)ZL;
#pragma unroll
    for (int i = 0; i < 4; ++i) d[tid + i * 512] = s[tid + i * 512]; }

  f32x4 acc[32];
#pragma unroll
  for (int f = 0; f < 32; ++f) acc[f] = (f32x4){0.f, 0.f, 0.f, 0.f};

  const int zr = wv * 16 + lane15;
  bf16x8 a[4];

#pragma unroll
  for (int c = 0; c < 4; ++c) {
    if (c) __syncthreads();
    { const u16x8* s = (const u16x8*)(WtD + c * 32768);
      u16x8* d = (u16x8*)WL;
#pragma unroll
      for (int i = 0; i < 4; ++i) d[tid + i * 512] = s[tid + i * 512]; }
    __syncthreads();
    if (c == 0) {
#pragma unroll
      for (int s = 0; s < 4; ++s)
        a[s] = *(const bf16x8*)(ZL + (((uint)zr * 256 + s * 64 + laneh * 16) ^ (uint)((zr & 7) << 4)));
    }
#pragma unroll
    for (int nf = 0; nf < 8; ++nf) {
      int n = nf * 16 + lane15;
      uint nb = (uint)n * 256 + laneh * 16, nsw = (uint)((n & 7) << 4);
#pragma unroll
      for (int s = 0; s < 4; ++s) {
        bf16x8 bfr = *(const bf16x8*)(WL + ((nb + s * 64) ^ nsw));
        acc[c * 8 + nf] = __builtin_amdgcn_mfma_f32_16x16x32_bf16(a[s], bfr, acc[c * 8 + nf], 0, 0, 0);
      }
    }
  }

#pragma unroll
  for (int r = 0; r < 4; ++r) {
    float m = acc[0][r];
#pragma unroll
    for (int f = 1; f < 32; ++f) m = fmaxf(m, acc[f][r]);
    m = fmaxf(m, __shfl_xor(m, 1)); m = fmaxf(m, __shfl_xor(m, 2));
    m = fmaxf(m, __shfl_xor(m, 4)); m = fmaxf(m, __shfl_xor(m, 8));
    float sum = 0.f;
#pragma unroll
    for (int f = 0; f < 32; ++f) { acc[f][r] = __expf(acc[f][r] - m); sum += acc[f][r]; }
    sum += __shfl_xor(sum, 1); sum += __shfl_xor(sum, 2);
    sum += __shfl_xor(sum, 4); sum += __shfl_xor(sum, 8);
    float inv = 1.0f / sum;
    int row = rb + wv * 16 + laneh * 4 + r;
    if (row < NN) {
      float* op = out + (size_t)row * INC + lane15;
#pragma unroll
      for (int f = 0; f < 32; ++f)
        op[(f >> 3) * 128 + (f & 7) * 16] = acc[f][r] * inv;
    }
  }
}

// ---------------- launch ----------------
extern "C" void kernel_launch(void* const* d_in, const int* in_sizes, int n_in,
                              void* d_out, int out_size, void* d_ws, size_t ws_size,
                              hipStream_t stream) {
  const float* x     = (const float*)d_in[0];
  const int*   ei    = (const int*)d_in[1];
  const float* W_enc = (const float*)d_in[2];
  const float* b_enc = (const float*)d_in[3];
  const float* W_dec = (const float*)d_in[4];
  float* out = (float*)d_out;

  const int E = in_sizes[1] / 2;
  const int* esrc = ei;
  const int* edst = ei + E;

  uint8_t* ws = (uint8_t*)d_ws;
  uint*  bucket_cursor = (uint*)(ws);                   // 782*64 B = 50 KB (padded x16)
  uint*  pairs         = (uint*)(ws + 0x10000);         // 782*4096*4 = 12.3 MB
  float* dis           = (float*)(ws + 0xC80000);       // 200 KB
  uint8_t* WtE         = ws + 0xD00000;                 // 128 KB
  uint8_t* WtD         = ws + 0xD20000;                 // 128 KB
  u16*   xws           = (u16*)(ws + 0xD40000);         // 12.8 MB
  uint8_t* zsw         = ws + 0x1A00000;                // 12.9 MB -> ends ~40 MB

  hipMemsetAsync(bucket_cursor, 0, NB * 64, stream);
  k_scatter_pairs<<<NWG, 256, 0, stream>>>(esrc, edst, E, bucket_cursor, pairs);
  k_deg_dis      <<<NB, 64, 0, stream>>>(bucket_cursor, pairs, dis);
  k_prep_enc     <<<16, 256, 0, stream>>>(W_enc, WtE);
  k_prep_dec     <<<16, 256, 0, stream>>>(W_dec, WtD);
  k_gemm1        <<<(NN + 127) / 128, 256, 0, stream>>>(x, WtE, dis, xws);
  k_agg          <<<NB, 256, 0, stream>>>(bucket_cursor, pairs, (const uint*)xws, dis, b_enc, zsw);
  k_decode       <<<(NN + 127) / 128, 512, 0, stream>>>(zsw, WtD, out);
}

// Round 6
// 339.774 us; speedup vs baseline: 4.8256x; 4.8256x over previous
//
#include <hip/hip_runtime.h>
#include <stdint.h>

#define NN   50000
#define INC  512
#define OUTC 128
#define NB   782      // ceil(50000/64) buckets of 64 nodes
#define CAP  4096     // per-bucket capacity (mean 2046, max ~2210)
#define NWG  256      // scatter workgroups

typedef unsigned int  uint;
typedef unsigned short u16;
typedef short bf16x8 __attribute__((ext_vector_type(8)));
typedef float f32x4  __attribute__((ext_vector_type(4)));
typedef u16   u16x8  __attribute__((ext_vector_type(8)));
typedef u16   u16x4  __attribute__((ext_vector_type(4)));

__device__ __forceinline__ u16 f2bf(float f) {        // RNE f32->bf16
  uint u = __float_as_uint(f);
  u += 0x7fffu + ((u >> 16) & 1u);
  return (u16)(u >> 16);
}
__device__ __forceinline__ float bflo(uint v) { return __uint_as_float(v << 16); }
__device__ __forceinline__ float bfhi(uint v) { return __uint_as_float(v & 0xffff0000u); }

// ---------------- bucketed edge binning ----------------
// pairs[b*CAP + i] = src | (dst_local << 16); bucket_cursor[b*16] = count(b)
__global__ __launch_bounds__(256) void k_scatter_pairs(const int* __restrict__ src,
                                                       const int* __restrict__ dst, int E,
                                                       uint* __restrict__ bucket_cursor,
                                                       uint* __restrict__ pairs) {
  __shared__ uint hist[NB];
  __shared__ uint base[NB];
  __shared__ uint cur[NB];
  const int t = threadIdx.x;
  const int chunk = (E + NWG - 1) / NWG;
  const int e0 = blockIdx.x * chunk;
  const int e1 = min(e0 + chunk, E);

  for (int i = t; i < NB; i += 256) hist[i] = 0;
  __syncthreads();
  for (int e = e0 + t; e < e1; e += 256) {
    int b = dst[e] >> 6;
    atomicAdd(&hist[b], 1u);
  }
  __syncthreads();
  for (int i = t; i < NB; i += 256) {
    uint c = hist[i];
    base[i] = c ? atomicAdd(&bucket_cursor[i * 16], c) : 0u;
    cur[i] = 0;
  }
  __syncthreads();
  for (int e = e0 + t; e < e1; e += 256) {
    int d = dst[e];
    int b = d >> 6;
    uint r = atomicAdd(&cur[b], 1u);
    uint off = base[b] + r;
    if (off < CAP) pairs[(size_t)b * CAP + off] = (uint)src[e] | ((uint)(d & 63) << 6 << 10);
  }
}

// ---------------- per-bucket counting sort -> sorted CSR + rs_packed + dis ----------------
__global__ __launch_bounds__(256) void k_sort(const uint* __restrict__ bucket_cursor,
                                              const uint* __restrict__ pairs,
                                              uint* __restrict__ csr,        // [NB*CAP] src ids
                                              uint* __restrict__ rs_packed,  // [NN] local_start | cnt<<16
                                              float* __restrict__ dis) {
  __shared__ uint plist[CAP];   // 16 KB
  __shared__ uint slist[CAP];   // 16 KB
  __shared__ uint cnt[64], pfx[64], cur[64];
  const int b = blockIdx.x, t = threadIdx.x;
  uint n_e = bucket_cursor[b * 16]; if (n_e > CAP) n_e = CAP;

  if (t < 64) cnt[t] = 0;
  __syncthreads();
  for (uint e = t; e < n_e; e += 256) {
    uint v = pairs[(size_t)b * CAP + e];
    plist[e] = v;
    atomicAdd(&cnt[(v >> 16) & 63u], 1u);
  }
  __syncthreads();
  if (t == 0) {
    uint run = 0;
    for (int i = 0; i < 64; ++i) { pfx[i] = run; run += cnt[i]; }
  }
  __syncthreads();
  if (t < 64) {
    cur[t] = pfx[t];
    int n = b * 64 + t;
    if (n < NN) {
      rs_packed[n] = pfx[t] | (cnt[t] << 16);
      dis[n] = rsqrtf((float)cnt[t] + 1.0f);
    }
  }
  __syncthreads();
  for (uint e = t; e < n_e; e += 256) {
    uint v = plist[e];
    uint pos = atomicAdd(&cur[(v >> 16) & 63u], 1u);
    slist[pos] = v & 0xffffu;
  }
  __syncthreads();
  for (uint e = t; e < n_e; e += 256) csr[(size_t)b * CAP + e] = slist[e];
}

// ---------------- weight prep: transpose + bf16 + pre-swizzle ----------------
__global__ __launch_bounds__(256) void k_prep_enc(const float* __restrict__ W,   // [512][128]
                                                  uint8_t* __restrict__ outw) {
  __shared__ float t[32][128];
  const int tid = threadIdx.x;
  const int k0 = blockIdx.x * 32;
#pragma unroll
  for (int r = 0; r < 16; ++r) {
    int e = r * 256 + tid;
    int kk = e >> 7, n = e & 127;
    t[kk][n] = W[(size_t)(k0 + kk) * 128 + n];
  }
  __syncthreads();
#pragma unroll
  for (int it = 0; it < 2; ++it) {
    int item = it * 256 + tid;
    int n = item & 127, kc = item >> 7;
    int kg = k0 + kc * 8;
    int q = kg >> 7, kin = kg & 127;
    u16x8 p;
#pragma unroll
    for (int j = 0; j < 8; ++j) p[j] = f2bf(t[kc * 8 + j][n]);
    *(u16x8*)(outw + q * 32768 + ((((uint)n * 256) + (uint)kin * 2) ^ (uint)((n & 7) << 4))) = p;
  }
}
__global__ __launch_bounds__(256) void k_prep_dec(const float* __restrict__ W,   // [128][512]
                                                  uint8_t* __restrict__ outw) {
  __shared__ float t[128][32];
  const int tid = threadIdx.x;
  const int n0 = blockIdx.x * 32;
#pragma unroll
  for (int r = 0; r < 16; ++r) {
    int e = r * 256 + tid;
    int k = e >> 5, nl = e & 31;
    t[k][nl] = W[(size_t)k * 512 + n0 + nl];
  }
  __syncthreads();
#pragma unroll
  for (int it = 0; it < 2; ++it) {
    int item = it * 256 + tid;
    int nl = item & 31, kc = item >> 5;
    int n = n0 + nl;
    int c = n >> 7, nin = n & 127;
    u16x8 p;
#pragma unroll
    for (int j = 0; j < 8; ++j) p[j] = f2bf(t[kc * 8 + j][nl]);
    *(u16x8*)(outw + c * 32768 + ((((uint)nin * 256) + (uint)kc * 16) ^ (uint)((nin & 7) << 4))) = p;
  }
}

// ---------------- GEMM1 (MFMA): xws = bf16( (x @ W_enc) * dis[row] ) ----------------
__global__ __launch_bounds__(256, 2) void k_gemm1(const float* __restrict__ x,
                                                  const uint8_t* __restrict__ WtE,
                                                  const float* __restrict__ dis,
                                                  u16* __restrict__ xws) {
  __shared__ __align__(16) uint8_t lds[49152];
  uint8_t* WL = lds;            // 32768
  uint8_t* XL = lds + 32768;    // 16384: [128 rows][64 k] bf16 swizzled
  const int tid = threadIdx.x, lane = tid & 63, wv = tid >> 6;
  const int lane15 = lane & 15, laneh = lane >> 4;
  const int rb = blockIdx.x * 128;

  f32x4 acc[2][8];
#pragma unroll
  for (int m = 0; m < 2; ++m)
#pragma unroll
    for (int n = 0; n < 8; ++n) acc[m][n] = (f32x4){0.f, 0.f, 0.f, 0.f};

  const int srow = tid >> 1;
  int grow = rb + srow; if (grow >= NN) grow = NN - 1;
  const int khalf = (tid & 1) * 32;
  const uint xb  = (uint)srow * 128 + (uint)khalf * 2;
  const uint xsw = (uint)((srow & 7) << 4);
  const int ar0 = wv * 32 + lane15, ar1 = ar0 + 16;

  for (int q = 0; q < 4; ++q) {           // K quarters of 128
    __syncthreads();
    { const u16x8* s = (const u16x8*)(WtE + q * 32768);
      u16x8* d = (u16x8*)WL;
#pragma unroll
      for (int i = 0; i < 8; ++i) d[tid + i * 256] = s[tid + i * 256]; }
#pragma unroll
    for (int step = 0; step < 2; ++step) {  // BK = 64
      if (step) __syncthreads();
      const float4* xs = (const float4*)(x + (size_t)grow * INC + q * 128 + step * 64 + khalf);
      float4 v[8];
#pragma unroll
      for (int j = 0; j < 8; ++j) v[j] = xs[j];
#pragma unroll
      for (int j = 0; j < 8; ++j) {
        u16x4 p; p.x = f2bf(v[j].x); p.y = f2bf(v[j].y); p.z = f2bf(v[j].z); p.w = f2bf(v[j].w);
        *(u16x4*)(XL + ((xb + j * 8) ^ xsw)) = p;
      }
      __syncthreads();
#pragma unroll
      for (int kk = 0; kk < 2; ++kk) {     // k-slices of 32
        bf16x8 a0 = *(const bf16x8*)(XL + (((uint)ar0 * 128 + kk * 64 + laneh * 16) ^ (uint)((ar0 & 7) << 4)));
        bf16x8 a1 = *(const bf16x8*)(XL + (((uint)ar1 * 128 + kk * 64 + laneh * 16) ^ (uint)((ar1 & 7) << 4)));
#pragma unroll
        for (int nf = 0; nf < 8; ++nf) {
          int n = nf * 16 + lane15;
          bf16x8 b = *(const bf16x8*)(WL + (((uint)n * 256 + step * 128 + kk * 64 + laneh * 16) ^ (uint)((n & 7) << 4)));
          acc[0][nf] = __builtin_amdgcn_mfma_f32_16x16x32_bf16(a0, b, acc[0][nf], 0, 0, 0);
          acc[1][nf] = __builtin_amdgcn_mfma_f32_16x16x32_bf16(a1, b, acc[1][nf], 0, 0, 0);
        }
      }
    }
  }
#pragma unroll
  for (int m = 0; m < 2; ++m) {
#pragma unroll
    for (int r = 0; r < 4; ++r) {
      int row = rb + wv * 32 + m * 16 + laneh * 4 + r;
      if (row < NN) {
        float dv = dis[row];
#pragma unroll
        for (int nf = 0; nf < 8; ++nf)
          xws[(size_t)row * 128 + nf * 16 + lane15] = f2bf(acc[m][nf][r] * dv);
      }
    }
  }
}

// ---------------- aggregate: per-node register gather (round-4 proven structure) ----------------
__global__ __launch_bounds__(64) void k_aggregate(const u16* __restrict__ xws,
                                                  const float* __restrict__ dis,
                                                  const uint* __restrict__ rs_packed,
                                                  const uint* __restrict__ csr,
                                                  const float* __restrict__ bias,
                                                  uint8_t* __restrict__ zsw) {
  const int i = blockIdx.x, lane = threadIdx.x;
  const uint v = rs_packed[i];
  const uint s0 = (uint)(i >> 6) * CAP + (v & 0xffffu);
  const uint s1 = s0 + (v >> 16);

  float a0 = 0.f, a1 = 0.f;
  uint j = s0;
  for (; j + 3 < s1; j += 4) {
    uint i0 = csr[j], i1 = csr[j + 1], i2 = csr[j + 2], i3 = csr[j + 3];
    uint v0 = *(const uint*)(xws + (size_t)i0 * 128 + lane * 2);
    uint v1 = *(const uint*)(xws + (size_t)i1 * 128 + lane * 2);
    uint v2 = *(const uint*)(xws + (size_t)i2 * 128 + lane * 2);
    uint v3 = *(const uint*)(xws + (size_t)i3 * 128 + lane * 2);
    a0 += bflo(v0) + bflo(v1) + bflo(v2) + bflo(v3);
    a1 += bfhi(v0) + bfhi(v1) + bfhi(v2) + bfhi(v3);
  }
  for (; j < s1; ++j) {
    uint vv = *(const uint*)(xws + (size_t)csr[j] * 128 + lane * 2);
    a0 += bflo(vv); a1 += bfhi(vv);
  }
  uint vs = *(const uint*)(xws + (size_t)i * 128 + lane * 2);
  float di = dis[i];
  float2 bb = *(const float2*)(bias + lane * 2);
  float z0 = fmaxf(di * (a0 + bflo(vs)) + bb.x, 0.f);
  float z1 = fmaxf(di * (a1 + bfhi(vs)) + bb.y, 0.f);
  uint pk = (uint)f2bf(z0) | ((uint)f2bf(z1) << 16);
  *(uint*)(zsw + ((((uint)i * 256) + (uint)lane * 4) ^ (uint)((i & 7) << 4))) = pk;
}

// ---------------- decode (MFMA): out = softmax(z @ W_dec) ----------------
__global__ __launch_bounds__(512, 2) void k_decode(const uint8_t* __restrict__ zsw,
                                                   const uint8_t* __restrict__ WtD,
                                                   float* __restrict__ out) {
  __shared__ __align__(16) uint8_t lds[65536];
  uint8_t* ZL = lds;
  uint8_t* WL = lds + 32768;
  const int tid = threadIdx.x, lane = tid & 63, wv = tid >> 6;
  const int lane15 = lane & 15, laneh = lane >> 4;
  const int rb = blockIdx.x * 128;

  { const u16x8* s = (const u16x8*)(zsw + (size_t)rb * 256);
    u16x8* d = (u16x8*)ZL;
#pragma unroll
    for (int i = 0; i < 4; ++i) d[tid + i * 512] = s[tid + i * 512]; }

  f32x4 acc[32];
#pragma unroll
  for (int f = 0; f < 32; ++f) acc[f] = (f32x4){0.f, 0.f, 0.f, 0.f};

  const int zr = wv * 16 + lane15;
  bf16x8 a[4];

#pragma unroll
  for (int c = 0; c < 4; ++c) {
    if (c) __syncthreads();
    { const u16x8* s = (const u16x8*)(WtD + c * 32768);
      u16x8* d = (u16x8*)WL;
#pragma unroll
      for (int i = 0; i < 4; ++i) d[tid + i * 512] = s[tid + i * 512]; }
    __syncthreads();
    if (c == 0) {
#pragma unroll
      for (int s = 0; s < 4; ++s)
        a[s] = *(const bf16x8*)(ZL + (((uint)zr * 256 + s * 64 + laneh * 16) ^ (uint)((zr & 7) << 4)));
    }
#pragma unroll
    for (int nf = 0; nf < 8; ++nf) {
      int n = nf * 16 + lane15;
      uint nb = (uint)n * 256 + laneh * 16, nsw = (uint)((n & 7) << 4);
#pragma unroll
      for (int s = 0; s < 4; ++s) {
        bf16x8 bfr = *(const bf16x8*)(WL + ((nb + s * 64) ^ nsw));
        acc[c * 8 + nf] = __builtin_amdgcn_mfma_f32_16x16x32_bf16(a[s], bfr, acc[c * 8 + nf], 0, 0, 0);
      }
    }
  }

#pragma unroll
  for (int r = 0; r < 4; ++r) {
    float m = acc[0][r];
#pragma unroll
    for (int f = 1; f < 32; ++f) m = fmaxf(m, acc[f][r]);
    m = fmaxf(m, __shfl_xor(m, 1)); m = fmaxf(m, __shfl_xor(m, 2));
    m = fmaxf(m, __shfl_xor(m, 4)); m = fmaxf(m, __shfl_xor(m, 8));
    float sum = 0.f;
#pragma unroll
    for (int f = 0; f < 32; ++f) { acc[f][r] = __expf(acc[f][r] - m); sum += acc[f][r]; }
    sum += __shfl_xor(sum, 1); sum += __shfl_xor(sum, 2);
    sum += __shfl_xor(sum, 4); sum += __shfl_xor(sum, 8);
    float inv = 1.0f / sum;
    int row = rb + wv * 16 + laneh * 4 + r;
    if (row < NN) {
      float* op = out + (size_t)row * INC + lane15;
#pragma unroll
      for (int f = 0; f < 32; ++f)
        op[(f >> 3) * 128 + (f & 7) * 16] = acc[f][r] * inv;
    }
  }
}

// ---------------- launch ----------------
extern "C" void kernel_launch(void* const* d_in, const int* in_sizes, int n_in,
                              void* d_out, int out_size, void* d_ws, size_t ws_size,
                              hipStream_t stream) {
  const float* x     = (const float*)d_in[0];
  const int*   ei    = (const int*)d_in[1];
  const float* W_enc = (const float*)d_in[2];
  const float* b_enc = (const float*)d_in[3];
  const float* W_dec = (const float*)d_in[4];
  float* out = (float*)d_out;

  const int E = in_sizes[1] / 2;
  const int* esrc = ei;
  const int* edst = ei + E;

  uint8_t* ws = (uint8_t*)d_ws;
  uint*  bucket_cursor = (uint*)(ws);                   // 50 KB (782 x 64B-padded)
  uint*  pairs         = (uint*)(ws + 0x10000);         // 12.8 MB
  uint*  csr           = (uint*)(ws + 0xC80000);        // 12.8 MB
  uint*  rs_packed     = (uint*)(ws + 0x1900000);       // 200 KB
  float* dis           = (float*)(ws + 0x1940000);      // 200 KB
  uint8_t* WtE         = ws + 0x1980000;                // 128 KB
  uint8_t* WtD         = ws + 0x19A0000;                // 128 KB
  u16*   xws           = (u16*)(ws + 0x19C0000);        // 12.8 MB
  uint8_t* zsw         = ws + 0x2600000;                // 12.8 MB -> ends ~50 MB

  hipMemsetAsync(bucket_cursor, 0, NB * 64, stream);
  k_scatter_pairs<<<NWG, 256, 0, stream>>>(esrc, edst, E, bucket_cursor, pairs);
  k_sort         <<<NB, 256, 0, stream>>>(bucket_cursor, pairs, csr, rs_packed, dis);
  k_prep_enc     <<<16, 256, 0, stream>>>(W_enc, WtE);
  k_prep_dec     <<<16, 256, 0, stream>>>(W_dec, WtD);
  k_gemm1        <<<(NN + 127) / 128, 256, 0, stream>>>(x, WtE, dis, xws);
  k_aggregate    <<<NN, 64, 0, stream>>>(xws, dis, rs_packed, csr, b_enc, zsw);
  k_decode       <<<(NN + 127) / 128, 512, 0, stream>>>(zsw, WtD, out);
}

// Round 7
// 339.657 us; speedup vs baseline: 4.8273x; 1.0003x over previous
//
#include <hip/hip_runtime.h>
#include <stdint.h>

#define NN   50000
#define INC  512
#define OUTC 128
#define NB   782      // ceil(50000/64) buckets of 64 nodes
#define CAP  4096     // per-bucket capacity (mean 2046, max ~2210)
#define NWG  256      // scatter workgroups

typedef unsigned int  uint;
typedef unsigned short u16;
typedef short bf16x8 __attribute__((ext_vector_type(8)));
typedef float f32x4  __attribute__((ext_vector_type(4)));
typedef u16   u16x8  __attribute__((ext_vector_type(8)));
typedef u16   u16x4  __attribute__((ext_vector_type(4)));

__device__ __forceinline__ u16 f2bf(float f) {        // RNE f32->bf16
  uint u = __float_as_uint(f);
  u += 0x7fffu + ((u >> 16) & 1u);
  return (u16)(u >> 16);
}
__device__ __forceinline__ float bflo(uint v) { return __uint_as_float(v << 16); }
__device__ __forceinline__ float bfhi(uint v) { return __uint_as_float(v & 0xffff0000u); }

// async global->LDS 16B copy; dest passed per-lane as base+lane*16 (linear)
__device__ __forceinline__ void gl_lds16(const void* g, void* l) {
  __builtin_amdgcn_global_load_lds(
      (const __attribute__((address_space(1))) uint*)g,
      (__attribute__((address_space(3))) uint*)l, 16, 0, 0);
}

// ---------------- bucketed edge binning ----------------
// pairs[b*CAP + i] = src | (dst_local << 16); bucket_cursor[b*16] = count(b)
__global__ __launch_bounds__(256) void k_scatter_pairs(const int* __restrict__ src,
                                                       const int* __restrict__ dst, int E,
                                                       uint* __restrict__ bucket_cursor,
                                                       uint* __restrict__ pairs) {
  __shared__ uint hist[NB];
  __shared__ uint base[NB];
  __shared__ uint cur[NB];
  const int t = threadIdx.x;
  const int chunk = (E + NWG - 1) / NWG;
  const int e0 = blockIdx.x * chunk;
  const int e1 = min(e0 + chunk, E);

  for (int i = t; i < NB; i += 256) hist[i] = 0;
  __syncthreads();
  for (int e = e0 + t; e < e1; e += 256) {
    int b = dst[e] >> 6;
    atomicAdd(&hist[b], 1u);
  }
  __syncthreads();
  for (int i = t; i < NB; i += 256) {
    uint c = hist[i];
    base[i] = c ? atomicAdd(&bucket_cursor[i * 16], c) : 0u;
    cur[i] = 0;
  }
  __syncthreads();
  for (int e = e0 + t; e < e1; e += 256) {
    int d = dst[e];
    int b = d >> 6;
    uint r = atomicAdd(&cur[b], 1u);
    uint off = base[b] + r;
    if (off < CAP) pairs[(size_t)b * CAP + off] = (uint)src[e] | ((uint)(d & 63) << 16);
  }
}

// ---------------- per-bucket counting sort -> sorted CSR + rs_packed + dis ----------------
__global__ __launch_bounds__(256) void k_sort(const uint* __restrict__ bucket_cursor,
                                              const uint* __restrict__ pairs,
                                              uint* __restrict__ csr,        // [NB*CAP] src ids
                                              uint* __restrict__ rs_packed,  // [NN] local_start | cnt<<16
                                              float* __restrict__ dis) {
  __shared__ uint plist[CAP];   // 16 KB
  __shared__ uint slist[CAP];   // 16 KB
  __shared__ uint cnt[64], pfx[64], cur[64];
  const int b = blockIdx.x, t = threadIdx.x;
  uint n_e = bucket_cursor[b * 16]; if (n_e > CAP) n_e = CAP;

  if (t < 64) cnt[t] = 0;
  __syncthreads();
  for (uint e = t; e < n_e; e += 256) {
    uint v = pairs[(size_t)b * CAP + e];
    plist[e] = v;
    atomicAdd(&cnt[(v >> 16) & 63u], 1u);
  }
  __syncthreads();
  if (t == 0) {
    uint run = 0;
    for (int i = 0; i < 64; ++i) { pfx[i] = run; run += cnt[i]; }
  }
  __syncthreads();
  if (t < 64) {
    cur[t] = pfx[t];
    int n = b * 64 + t;
    if (n < NN) {
      rs_packed[n] = pfx[t] | (cnt[t] << 16);
      dis[n] = rsqrtf((float)cnt[t] + 1.0f);
    }
  }
  __syncthreads();
  for (uint e = t; e < n_e; e += 256) {
    uint v = plist[e];
    uint pos = atomicAdd(&cur[(v >> 16) & 63u], 1u);
    slist[pos] = v & 0xffffu;
  }
  __syncthreads();
  for (uint e = t; e < n_e; e += 256) csr[(size_t)b * CAP + e] = slist[e];
}

// ---------------- fused weight prep: transpose + bf16 + pre-swizzle ----------------
// Output layout (both): [4 chunks][128 rows][128 k] bf16, row stride 256 B,
// byte-in-chunk = (row*256 + k*2) ^ ((row&7)<<4).
__global__ __launch_bounds__(256) void k_prep(const float* __restrict__ We,   // [512][128]
                                              const float* __restrict__ Wd,   // [128][512]
                                              uint8_t* __restrict__ oE,
                                              uint8_t* __restrict__ oD) {
  __shared__ float t[4096];
  const int tid = threadIdx.x;
  if (blockIdx.x < 16) {
    const int k0 = blockIdx.x * 32;
#pragma unroll
    for (int r = 0; r < 16; ++r) {
      int e = r * 256 + tid;
      int kk = e >> 7, n = e & 127;
      t[kk * 128 + n] = We[(size_t)(k0 + kk) * 128 + n];
    }
    __syncthreads();
#pragma unroll
    for (int it = 0; it < 2; ++it) {
      int item = it * 256 + tid;
      int n = item & 127, kc = item >> 7;
      int kg = k0 + kc * 8;
      int q = kg >> 7, kin = kg & 127;
      u16x8 p;
#pragma unroll
      for (int j = 0; j < 8; ++j) p[j] = f2bf(t[(kc * 8 + j) * 128 + n]);
      *(u16x8*)(oE + q * 32768 + ((((uint)n * 256) + (uint)kin * 2) ^ (uint)((n & 7) << 4))) = p;
    }
  } else {
    const int n0 = (blockIdx.x - 16) * 32;
#pragma unroll
    for (int r = 0; r < 16; ++r) {
      int e = r * 256 + tid;
      int k = e >> 5, nl = e & 31;
      t[k * 32 + nl] = Wd[(size_t)k * 512 + n0 + nl];
    }
    __syncthreads();
#pragma unroll
    for (int it = 0; it < 2; ++it) {
      int item = it * 256 + tid;
      int nl = item & 31, kc = item >> 5;
      int n = n0 + nl;
      int c = n >> 7, nin = n & 127;
      u16x8 p;
#pragma unroll
      for (int j = 0; j < 8; ++j) p[j] = f2bf(t[(kc * 8 + j) * 32 + nl]);
      *(u16x8*)(oD + c * 32768 + ((((uint)nin * 256) + (uint)kc * 16) ^ (uint)((nin & 7) << 4))) = p;
    }
  }
}

// ---------------- GEMM1 (MFMA): xws = bf16( (x @ W_enc) * dis[row] ) ----------------
// 128x128 tile, 4 waves x (32 rows x 128 cols). LDS: W-chunk 32KB + x-tile 16KB = 48KB.
__global__ __launch_bounds__(256, 2) void k_gemm1(const float* __restrict__ x,
                                                  const uint8_t* __restrict__ WtE,
                                                  const float* __restrict__ dis,
                                                  u16* __restrict__ xws) {
  __shared__ __align__(16) uint8_t lds[49152];
  uint8_t* WL = lds;            // 32768
  uint8_t* XL = lds + 32768;    // 16384: [128 rows][64 k] bf16 swizzled
  const int tid = threadIdx.x, lane = tid & 63, wv = tid >> 6;
  const int lane15 = lane & 15, laneh = lane >> 4;
  const int rb = blockIdx.x * 128;

  f32x4 acc[2][8];
#pragma unroll
  for (int m = 0; m < 2; ++m)
#pragma unroll
    for (int n = 0; n < 8; ++n) acc[m][n] = (f32x4){0.f, 0.f, 0.f, 0.f};

  const int srow = tid >> 1;
  int grow = rb + srow; if (grow >= NN) grow = NN - 1;
  const int khalf = (tid & 1) * 32;
  const uint xb  = (uint)srow * 128 + (uint)khalf * 2;
  const uint xsw = (uint)((srow & 7) << 4);
  const int ar0 = wv * 32 + lane15, ar1 = ar0 + 16;

  for (int q = 0; q < 4; ++q) {           // K quarters of 128
    __syncthreads();
    { const uint8_t* s = WtE + q * 32768;     // async DMA: pre-swizzled, linear copy
#pragma unroll
      for (int i = 0; i < 8; ++i)
        gl_lds16(s + tid * 16 + i * 4096, WL + tid * 16 + i * 4096); }
#pragma unroll
    for (int step = 0; step < 2; ++step) {  // BK = 64
      if (step) __syncthreads();
      const float4* xs = (const float4*)(x + (size_t)grow * INC + q * 128 + step * 64 + khalf);
      float4 v[8];
#pragma unroll
      for (int j = 0; j < 8; ++j) v[j] = xs[j];
#pragma unroll
      for (int j = 0; j < 8; ++j) {
        u16x4 p; p.x = f2bf(v[j].x); p.y = f2bf(v[j].y); p.z = f2bf(v[j].z); p.w = f2bf(v[j].w);
        *(u16x4*)(XL + ((xb + j * 8) ^ xsw)) = p;
      }
      __syncthreads();                     // drains vmcnt (W DMA) + lgkm (x writes)
#pragma unroll
      for (int kk = 0; kk < 2; ++kk) {     // k-slices of 32
        bf16x8 a0 = *(const bf16x8*)(XL + (((uint)ar0 * 128 + kk * 64 + laneh * 16) ^ (uint)((ar0 & 7) << 4)));
        bf16x8 a1 = *(const bf16x8*)(XL + (((uint)ar1 * 128 + kk * 64 + laneh * 16) ^ (uint)((ar1 & 7) << 4)));
#pragma unroll
        for (int nf = 0; nf < 8; ++nf) {
          int n = nf * 16 + lane15;
          bf16x8 b = *(const bf16x8*)(WL + (((uint)n * 256 + step * 128 + kk * 64 + laneh * 16) ^ (uint)((n & 7) << 4)));
          acc[0][nf] = __builtin_amdgcn_mfma_f32_16x16x32_bf16(a0, b, acc[0][nf], 0, 0, 0);
          acc[1][nf] = __builtin_amdgcn_mfma_f32_16x16x32_bf16(a1, b, acc[1][nf], 0, 0, 0);
        }
      }
    }
  }
#pragma unroll
  for (int m = 0; m < 2; ++m) {
#pragma unroll
    for (int r = 0; r < 4; ++r) {
      int row = rb + wv * 32 + m * 16 + laneh * 4 + r;
      if (row < NN) {
        float dv = dis[row];
#pragma unroll
        for (int nf = 0; nf < 8; ++nf)
          xws[(size_t)row * 128 + nf * 16 + lane15] = f2bf(acc[m][nf][r] * dv);
      }
    }
  }
}

// ---------------- aggregate: per-node register gather (2 nodes/block, unroll 8) ----------------
__global__ __launch_bounds__(128) void k_aggregate(const u16* __restrict__ xws,
                                                   const float* __restrict__ dis,
                                                   const uint* __restrict__ rs_packed,
                                                   const uint* __restrict__ csr,
                                                   const float* __restrict__ bias,
                                                   uint8_t* __restrict__ zsw) {
  const int i = blockIdx.x * 2 + (threadIdx.x >> 6);
  const int lane = threadIdx.x & 63;
  const uint v = rs_packed[i];
  const uint s0 = (uint)(i >> 6) * CAP + (v & 0xffffu);
  const uint s1 = s0 + (v >> 16);

  float a0 = 0.f, a1 = 0.f;
  uint j = s0;
  for (; j + 7 < s1; j += 8) {
    uint idx[8], vv[8];
#pragma unroll
    for (int t = 0; t < 8; ++t) idx[t] = csr[j + t];
#pragma unroll
    for (int t = 0; t < 8; ++t) vv[t] = *(const uint*)(xws + (size_t)idx[t] * 128 + lane * 2);
#pragma unroll
    for (int t = 0; t < 8; ++t) { a0 += bflo(vv[t]); a1 += bfhi(vv[t]); }
  }
  for (; j < s1; ++j) {
    uint vv = *(const uint*)(xws + (size_t)csr[j] * 128 + lane * 2);
    a0 += bflo(vv); a1 += bfhi(vv);
  }
  uint vs = *(const uint*)(xws + (size_t)i * 128 + lane * 2);
  float di = dis[i];
  float2 bb = *(const float2*)(bias + lane * 2);
  float z0 = fmaxf(di * (a0 + bflo(vs)) + bb.x, 0.f);
  float z1 = fmaxf(di * (a1 + bfhi(vs)) + bb.y, 0.f);
  uint pk = (uint)f2bf(z0) | ((uint)f2bf(z1) << 16);
  *(uint*)(zsw + ((((uint)i * 256) + (uint)lane * 4) ^ (uint)((i & 7) << 4))) = pk;
}

// ---------------- decode (MFMA): out = softmax(z @ W_dec) ----------------
// 4 waves x 16 rows = 64 rows/block. K=128 in registers; N=512 in 4 chunks.
// LDS: z-tile 16KB + W-chunk 32KB = 48KB -> 3 blocks/CU (VGPR permitting).
__global__ __launch_bounds__(256, 2) void k_decode(const uint8_t* __restrict__ zsw,
                                                   const uint8_t* __restrict__ WtD,
                                                   float* __restrict__ out) {
  __shared__ __align__(16) uint8_t lds[49152];
  uint8_t* ZL = lds;            // 16384
  uint8_t* WL = lds + 16384;    // 32768
  const int tid = threadIdx.x, lane = tid & 63, wv = tid >> 6;
  const int lane15 = lane & 15, laneh = lane >> 4;
  const int rb = blockIdx.x * 64;

  { const uint8_t* s = zsw + (size_t)rb * 256;    // async DMA, pre-swizzled
#pragma unroll
    for (int i = 0; i < 4; ++i)
      gl_lds16(s + tid * 16 + i * 4096, ZL + tid * 16 + i * 4096); }

  f32x4 acc[32];
#pragma unroll
  for (int f = 0; f < 32; ++f) acc[f] = (f32x4){0.f, 0.f, 0.f, 0.f};

  const int zr = wv * 16 + lane15;
  bf16x8 a[4];

#pragma unroll
  for (int c = 0; c < 4; ++c) {
    if (c) __syncthreads();              // waves done reading prev W chunk
    { const uint8_t* s = WtD + c * 32768;
#pragma unroll
      for (int i = 0; i < 8; ++i)
        gl_lds16(s + tid * 16 + i * 4096, WL + tid * 16 + i * 4096); }
    __syncthreads();                     // drains vmcnt -> z (c==0) and W ready
    if (c == 0) {
#pragma unroll
      for (int s = 0; s < 4; ++s)
        a[s] = *(const bf16x8*)(ZL + (((uint)zr * 256 + s * 64 + laneh * 16) ^ (uint)((zr & 7) << 4)));
    }
#pragma unroll
    for (int nf = 0; nf < 8; ++nf) {
      int n = nf * 16 + lane15;
      uint nb = (uint)n * 256 + laneh * 16, nsw = (uint)((n & 7) << 4);
#pragma unroll
      for (int s = 0; s < 4; ++s) {
        bf16x8 bfr = *(const bf16x8*)(WL + ((nb + s * 64) ^ nsw));
        acc[c * 8 + nf] = __builtin_amdgcn_mfma_f32_16x16x32_bf16(a[s], bfr, acc[c * 8 + nf], 0, 0, 0);
      }
    }
  }

#pragma unroll
  for (int r = 0; r < 4; ++r) {
    float m = acc[0][r];
#pragma unroll
    for (int f = 1; f < 32; ++f) m = fmaxf(m, acc[f][r]);
    m = fmaxf(m, __shfl_xor(m, 1)); m = fmaxf(m, __shfl_xor(m, 2));
    m = fmaxf(m, __shfl_xor(m, 4)); m = fmaxf(m, __shfl_xor(m, 8));
    float sum = 0.f;
#pragma unroll
    for (int f = 0; f < 32; ++f) { acc[f][r] = __expf(acc[f][r] - m); sum += acc[f][r]; }
    sum += __shfl_xor(sum, 1); sum += __shfl_xor(sum, 2);
    sum += __shfl_xor(sum, 4); sum += __shfl_xor(sum, 8);
    float inv = 1.0f / sum;
    int row = rb + wv * 16 + laneh * 4 + r;
    if (row < NN) {
      float* op = out + (size_t)row * INC + lane15;
#pragma unroll
      for (int f = 0; f < 32; ++f)
        op[(f >> 3) * 128 + (f & 7) * 16] = acc[f][r] * inv;
    }
  }
}

// ---------------- launch ----------------
extern "C" void kernel_launch(void* const* d_in, const int* in_sizes, int n_in,
                              void* d_out, int out_size, void* d_ws, size_t ws_size,
                              hipStream_t stream) {
  const float* x     = (const float*)d_in[0];
  const int*   ei    = (const int*)d_in[1];
  const float* W_enc = (const float*)d_in[2];
  const float* b_enc = (const float*)d_in[3];
  const float* W_dec = (const float*)d_in[4];
  float* out = (float*)d_out;

  const int E = in_sizes[1] / 2;
  const int* esrc = ei;
  const int* edst = ei + E;

  uint8_t* ws = (uint8_t*)d_ws;
  uint*  bucket_cursor = (uint*)(ws);                   // 50 KB (782 x 64B-padded)
  uint*  pairs         = (uint*)(ws + 0x10000);         // 12.8 MB
  uint*  csr           = (uint*)(ws + 0xC80000);        // 12.8 MB
  uint*  rs_packed     = (uint*)(ws + 0x1900000);       // 200 KB
  float* dis           = (float*)(ws + 0x1940000);      // 200 KB
  uint8_t* WtE         = ws + 0x1980000;                // 128 KB
  uint8_t* WtD         = ws + 0x19A0000;                // 128 KB
  u16*   xws           = (u16*)(ws + 0x19C0000);        // 12.8 MB
  uint8_t* zsw         = ws + 0x2600000;                // 12.8 MB -> ends ~50 MB

  hipMemsetAsync(bucket_cursor, 0, NB * 64, stream);
  k_scatter_pairs<<<NWG, 256, 0, stream>>>(esrc, edst, E, bucket_cursor, pairs);
  k_sort         <<<NB, 256, 0, stream>>>(bucket_cursor, pairs, csr, rs_packed, dis);
  k_prep         <<<32, 256, 0, stream>>>(W_enc, W_dec, WtE, WtD);
  k_gemm1        <<<(NN + 127) / 128, 256, 0, stream>>>(x, WtE, dis, xws);
  k_aggregate    <<<NN / 2, 128, 0, stream>>>(xws, dis, rs_packed, csr, b_enc, zsw);
  k_decode       <<<(NN + 63) / 64, 256, 0, stream>>>(zsw, WtD, out);
}